// Round 2
// baseline (662.111 us; speedup 1.0000x reference)
//
#include <hip/hip_runtime.h>
#include <math.h>

#define BB 32
#define DD 512
#define MM 1024
#define NN 1024

typedef float f32x4 __attribute__((ext_vector_type(4)));
typedef short bf16x8 __attribute__((ext_vector_type(8)));

// float -> bf16 (RNE) bit trick; inputs are finite (no NaN handling needed)
__device__ __forceinline__ short f2bf(float x) {
    unsigned int u = __float_as_uint(x);
    u += 0x7FFFu + ((u >> 16) & 1u);
    return (short)(u >> 16);
}
__device__ __forceinline__ float bf2f(short h) {
    return __uint_as_float(((unsigned int)(unsigned short)h) << 16);
}

// ---------------------------------------------------------------------------
// Kernel 1: column norms of (B,D,M)/(B,D,N) embeddings + v init (v = 1/N)
// ---------------------------------------------------------------------------
__global__ __launch_bounds__(256)
void norms_init_kernel(const float* __restrict__ srcE, const float* __restrict__ tgtE,
                       float* __restrict__ w1, float* __restrict__ w2, float* __restrict__ v)
{
    const int idx = blockIdx.x * 256 + threadIdx.x;     // 0..65535
    const float* e; float* w; int r;
    if (idx < 32768) { e = srcE; w = w1; r = idx; v[idx] = 1.0f / 1024.0f; }
    else             { e = tgtE; w = w2; r = idx - 32768; }
    const int b = r >> 10;
    const int m = r & 1023;
    const float* p = e + (size_t)b * (DD * MM) + m;
    float acc = 0.f;
    #pragma unroll 8
    for (int d = 0; d < DD; ++d) {
        const float x = p[(size_t)d * MM];
        acc = fmaf(x, x, acc);
    }
    w[r] = sqrtf(acc);
}

// ---------------------------------------------------------------------------
// Kernel 2: split-bf16 MFMA GEMM (x = hi + lo; dot = hi*hi + hi*lo + lo*hi)
// gives ~fp32 precision at bf16 MFMA rate. Fused epilogue K = exp((sim-1)/l)
// written fp32 into the P region of d_out. 128x128 tile, BK=64,
// XOR-swizzled LDS [row][k] layout (conflict-even b128 writes & reads).
// ---------------------------------------------------------------------------
__global__ __launch_bounds__(256, 2)
void gemm_kexp_kernel(const float* __restrict__ Ae, const float* __restrict__ Be,
                      const float* __restrict__ w1, const float* __restrict__ w2,
                      const float* __restrict__ lp, float* __restrict__ Kout)
{
    __shared__ short As[2][128 * 64];   // [0]=hi, [1]=lo
    __shared__ short Bs[2][128 * 64];

    const int tid  = threadIdx.x;
    const int lane = tid & 63;
    const int wave = tid >> 6;
    const int m0 = blockIdx.x * 128;
    const int n0 = blockIdx.y * 128;
    const int b  = blockIdx.z;
    const int wm = (wave & 1) * 64;
    const int wn = (wave >> 1) * 64;
    const int m16  = lane & 15;
    const int quad = lane >> 4;

    const float* Ab = Ae + (size_t)b * DD * MM;
    const float* Bb = Be + (size_t)b * DD * NN;

    f32x4 acc[4][4];
    #pragma unroll
    for (int i = 0; i < 4; ++i)
        #pragma unroll
        for (int j = 0; j < 4; ++j)
            acc[i][j] = (f32x4){0.f, 0.f, 0.f, 0.f};

    const int sm = tid & 127;   // tile row (m or n) staged by this thread
    const int kh = tid >> 7;    // 0..1
    const int sw = sm & 7;      // xor swizzle key

    for (int kt = 0; kt < DD; kt += 64) {
        __syncthreads();
        // ---- stage: gather-transpose global (k-major) -> LDS hi/lo bf16 ----
        #pragma unroll
        for (int t = 0; t < 4; ++t) {
            const int kg = kh + 2 * t;                       // 0..7 (8 k's each)
            const float* ap = Ab + (size_t)(kt + kg * 8) * MM + m0 + sm;
            const float* bp = Bb + (size_t)(kt + kg * 8) * NN + n0 + sm;
            float av[8], bv[8];
            #pragma unroll
            for (int j = 0; j < 8; ++j) av[j] = ap[(size_t)j * MM];
            #pragma unroll
            for (int j = 0; j < 8; ++j) bv[j] = bp[(size_t)j * NN];
            bf16x8 pah, pal, pbh, pbl;
            #pragma unroll
            for (int j = 0; j < 8; ++j) {
                const short ha = f2bf(av[j]);
                pah[j] = ha; pal[j] = f2bf(av[j] - bf2f(ha));
                const short hb = f2bf(bv[j]);
                pbh[j] = hb; pbl[j] = f2bf(bv[j] - bf2f(hb));
            }
            const int off = sm * 64 + ((kg ^ sw) << 3);
            *reinterpret_cast<bf16x8*>(&As[0][off]) = pah;
            *reinterpret_cast<bf16x8*>(&As[1][off]) = pal;
            *reinterpret_cast<bf16x8*>(&Bs[0][off]) = pbh;
            *reinterpret_cast<bf16x8*>(&Bs[1][off]) = pbl;
        }
        __syncthreads();
        // ---- compute: 2 k-steps of 32, 48 MFMAs each (hh, h*lo, lo*h) ----
        #pragma unroll
        for (int ks = 0; ks < 2; ++ks) {
            const int kg = ks * 4 + quad;
            bf16x8 ah[4], bh[4], tl[4];
            #pragma unroll
            for (int i = 0; i < 4; ++i) {
                const int rm = wm + i * 16 + m16;
                ah[i] = *reinterpret_cast<const bf16x8*>(&As[0][rm * 64 + ((kg ^ (rm & 7)) << 3)]);
                const int rn = wn + i * 16 + m16;
                bh[i] = *reinterpret_cast<const bf16x8*>(&Bs[0][rn * 64 + ((kg ^ (rn & 7)) << 3)]);
            }
            #pragma unroll
            for (int i = 0; i < 4; ++i)
                #pragma unroll
                for (int j = 0; j < 4; ++j)
                    acc[i][j] = __builtin_amdgcn_mfma_f32_16x16x32_bf16(ah[i], bh[j], acc[i][j], 0, 0, 0);
            #pragma unroll
            for (int i = 0; i < 4; ++i) {
                const int rn = wn + i * 16 + m16;
                tl[i] = *reinterpret_cast<const bf16x8*>(&Bs[1][rn * 64 + ((kg ^ (rn & 7)) << 3)]);
            }
            #pragma unroll
            for (int i = 0; i < 4; ++i)
                #pragma unroll
                for (int j = 0; j < 4; ++j)
                    acc[i][j] = __builtin_amdgcn_mfma_f32_16x16x32_bf16(ah[i], tl[j], acc[i][j], 0, 0, 0);
            #pragma unroll
            for (int i = 0; i < 4; ++i) {
                const int rm = wm + i * 16 + m16;
                tl[i] = *reinterpret_cast<const bf16x8*>(&As[1][rm * 64 + ((kg ^ (rm & 7)) << 3)]);
            }
            #pragma unroll
            for (int i = 0; i < 4; ++i)
                #pragma unroll
                for (int j = 0; j < 4; ++j)
                    acc[i][j] = __builtin_amdgcn_mfma_f32_16x16x32_bf16(tl[i], bh[j], acc[i][j], 0, 0, 0);
        }
    }

    // ---- epilogue: K = exp((dot/denom - 1) * 1/max(l,1e-8)) ----
    const float inv_l = 1.0f / fmaxf(lp[0], 1e-8f);
    float w2v[4];
    #pragma unroll
    for (int j = 0; j < 4; ++j) w2v[j] = w2[b * NN + n0 + wn + j * 16 + m16];
    float* Kb = Kout + ((size_t)b << 20);
    #pragma unroll
    for (int i = 0; i < 4; ++i) {
        #pragma unroll
        for (int r = 0; r < 4; ++r) {
            const int m = m0 + wm + i * 16 + quad * 4 + r;
            const float w1v = w1[b * MM + m];
            #pragma unroll
            for (int j = 0; j < 4; ++j) {
                const float dot = acc[i][j][r];
                const float den = fmaxf(w1v * w2v[j], 1e-6f);
                const float kv  = __expf((dot / den - 1.0f) * inv_l);
                Kb[(size_t)m * NN + (n0 + wn + j * 16 + m16)] = kv;
            }
        }
    }
}

// ---------------------------------------------------------------------------
// Kernel 3a: u = (a / clamp(K @ v, 1e-8))^fi      (one wave per row)
// ---------------------------------------------------------------------------
__global__ __launch_bounds__(256)
void u_update_kernel(const float* __restrict__ Kmat, const float* __restrict__ v,
                     float* __restrict__ u, const float* __restrict__ lp,
                     const float* __restrict__ rp)
{
    const int gid  = (blockIdx.x * 256 + threadIdx.x) >> 6;  // global wave = (b,m)
    const int lane = threadIdx.x & 63;
    const int b = gid >> 10;
    const float4* row = reinterpret_cast<const float4*>(Kmat + ((size_t)gid << 10));
    const float4* vb  = reinterpret_cast<const float4*>(v + (b << 10));
    float4 a = {0.f, 0.f, 0.f, 0.f};
    #pragma unroll
    for (int it = 0; it < 4; ++it) {
        const float4 k4 = row[it * 64 + lane];
        const float4 v4 = vb[it * 64 + lane];
        a.x = fmaf(k4.x, v4.x, a.x);
        a.y = fmaf(k4.y, v4.y, a.y);
        a.z = fmaf(k4.z, v4.z, a.z);
        a.w = fmaf(k4.w, v4.w, a.w);
    }
    float s = (a.x + a.y) + (a.z + a.w);
    #pragma unroll
    for (int off = 32; off > 0; off >>= 1) s += __shfl_down(s, off);
    if (lane == 0) {
        const float l = lp[0], rho = rp[0];
        const float fi = rho / fmaxf(rho + l, 1e-8f);
        u[gid] = __powf((1.0f / 1024.0f) / fmaxf(s, 1e-8f), fi);
    }
}

// ---------------------------------------------------------------------------
// Kernel 3b: partial column sums of K^T @ u  (m split 8-ways, deterministic)
// grid (4 n-chunks, 8 m-splits, 32 b); block = 4 waves, wave covers 32 rows
// ---------------------------------------------------------------------------
__global__ __launch_bounds__(256)
void v_partial_kernel(const float* __restrict__ Kmat, const float* __restrict__ u,
                      float* __restrict__ part)
{
    const int nc = blockIdx.x;          // 0..3   (256 cols each)
    const int ms = blockIdx.y;          // 0..7   (128 rows each)
    const int b  = blockIdx.z;          // 0..31
    const int wv = threadIdx.x >> 6, lane = threadIdx.x & 63;
    const int mstart = ms * 128 + wv * 32;
    const float4* Kb = reinterpret_cast<const float4*>(Kmat + ((size_t)b << 20));
    const float* ub = u + (b << 10);
    float4 a = {0.f, 0.f, 0.f, 0.f};
    #pragma unroll 4
    for (int mm = 0; mm < 32; ++mm) {
        const int m = mstart + mm;
        const float um = ub[m];
        const float4 k4 = Kb[m * 256 + nc * 64 + lane];
        a.x = fmaf(k4.x, um, a.x);
        a.y = fmaf(k4.y, um, a.y);
        a.z = fmaf(k4.z, um, a.z);
        a.w = fmaf(k4.w, um, a.w);
    }
    __shared__ float4 red[4][64];
    red[wv][lane] = a;
    __syncthreads();
    if (wv == 0) {
        float4 s = red[0][lane];
        #pragma unroll
        for (int w = 1; w < 4; ++w) {
            s.x += red[w][lane].x; s.y += red[w][lane].y;
            s.z += red[w][lane].z; s.w += red[w][lane].w;
        }
        reinterpret_cast<float4*>(part)[(ms * 32 + b) * 256 + nc * 64 + lane] = s;
    }
}

// ---------------------------------------------------------------------------
// Kernel 3c: v = (b / clamp(sum partials, 1e-8))^fi
// ---------------------------------------------------------------------------
__global__ __launch_bounds__(256)
void v_finalize_kernel(const float* __restrict__ part, float* __restrict__ v,
                       const float* __restrict__ lp, const float* __restrict__ rp)
{
    const int idx = blockIdx.x * 256 + threadIdx.x;   // 0..32767 = b*1024+n
    float s = 0.f;
    #pragma unroll
    for (int ms = 0; ms < 8; ++ms) s += part[ms * 32768 + idx];
    const float l = lp[0], rho = rp[0];
    const float fi = rho / fmaxf(rho + l, 1e-8f);
    v[idx] = __powf((1.0f / 1024.0f) / fmaxf(s, 1e-8f), fi);
}

// ---------------------------------------------------------------------------
// Kernel 4: P = u*K*v (in-place over K), row sums, weighted_ref
// one wave per row
// ---------------------------------------------------------------------------
__global__ __launch_bounds__(256)
void p_pass_kernel(float* __restrict__ Kmat, const float* __restrict__ u,
                   const float* __restrict__ v, const float* __restrict__ tgt,
                   float* __restrict__ rowb, float* __restrict__ wref)
{
    const int gid  = (blockIdx.x * 256 + threadIdx.x) >> 6;
    const int lane = threadIdx.x & 63;
    const int b = gid >> 10;
    float4* row = reinterpret_cast<float4*>(Kmat + ((size_t)gid << 10));
    const float4* vb = reinterpret_cast<const float4*>(v + (b << 10));
    const float4* tb = reinterpret_cast<const float4*>(tgt + (size_t)b * 3072);
    const float um = u[gid];
    float4 s4 = {0,0,0,0}, x4 = {0,0,0,0}, y4 = {0,0,0,0}, z4 = {0,0,0,0};
    #pragma unroll
    for (int it = 0; it < 4; ++it) {
        const int i = it * 64 + lane;
        const float4 k4 = row[i];
        const float4 v4 = vb[i];
        float4 p;
        p.x = um * k4.x * v4.x;
        p.y = um * k4.y * v4.y;
        p.z = um * k4.z * v4.z;
        p.w = um * k4.w * v4.w;
        row[i] = p;
        const float4 tx = tb[i], ty = tb[256 + i], tz = tb[512 + i];
        s4.x += p.x; s4.y += p.y; s4.z += p.z; s4.w += p.w;
        x4.x = fmaf(p.x, tx.x, x4.x); x4.y = fmaf(p.y, tx.y, x4.y);
        x4.z = fmaf(p.z, tx.z, x4.z); x4.w = fmaf(p.w, tx.w, x4.w);
        y4.x = fmaf(p.x, ty.x, y4.x); y4.y = fmaf(p.y, ty.y, y4.y);
        y4.z = fmaf(p.z, ty.z, y4.z); y4.w = fmaf(p.w, ty.w, y4.w);
        z4.x = fmaf(p.x, tz.x, z4.x); z4.y = fmaf(p.y, tz.y, z4.y);
        z4.z = fmaf(p.z, tz.z, z4.z); z4.w = fmaf(p.w, tz.w, z4.w);
    }
    float s = (s4.x + s4.y) + (s4.z + s4.w);
    float x = (x4.x + x4.y) + (x4.z + x4.w);
    float y = (y4.x + y4.y) + (y4.z + y4.w);
    float z = (z4.x + z4.y) + (z4.z + z4.w);
    #pragma unroll
    for (int off = 32; off > 0; off >>= 1) {
        s += __shfl_down(s, off);
        x += __shfl_down(x, off);
        y += __shfl_down(y, off);
        z += __shfl_down(z, off);
    }
    if (lane == 0) {
        rowb[gid] = s;
        const float inv = 1.0f / (s + 1e-6f);
        wref[gid * 3 + 0] = x * inv;
        wref[gid * 3 + 1] = y * inv;
        wref[gid * 3 + 2] = z * inv;
    }
}

// ---------------------------------------------------------------------------
// Kernel 5: per-batch weighted centroids + covariance (one block per batch)
// ---------------------------------------------------------------------------
__device__ __forceinline__ float block_reduce_sum(float x, float* lds4, int wv, int lane)
{
    #pragma unroll
    for (int off = 32; off > 0; off >>= 1) x += __shfl_down(x, off);
    __syncthreads();
    if (lane == 0) lds4[wv] = x;
    __syncthreads();
    return (lds4[0] + lds4[1]) + (lds4[2] + lds4[3]);
}

__global__ __launch_bounds__(256)
void kabsch_stats_kernel(const float* __restrict__ rowb, const float* __restrict__ wref,
                         const float* __restrict__ src, float* __restrict__ cov,
                         float* __restrict__ ca, float* __restrict__ cb)
{
    __shared__ float lds4[4];
    const int b = blockIdx.x, tid = threadIdx.x;
    const int wv = tid >> 6, lane = tid & 63;
    float r[4], w[4], ax[4], ay[4], az[4], bx[4], by[4], bz[4];
    float rsum = 0.f;
    #pragma unroll
    for (int i = 0; i < 4; ++i) {
        const int m = tid + 256 * i;
        r[i] = rowb[(b << 10) + m];
        rsum += r[i];
    }
    const float total = block_reduce_sum(rsum, lds4, wv, lane);
    const float inv = 1.0f / (total + 1e-6f);
    #pragma unroll
    for (int i = 0; i < 4; ++i) {
        const int m = tid + 256 * i;
        w[i]  = r[i] * inv;
        ax[i] = src[b * 3072 + m];
        ay[i] = src[b * 3072 + 1024 + m];
        az[i] = src[b * 3072 + 2048 + m];
        bx[i] = wref[((b << 10) + m) * 3 + 0];
        by[i] = wref[((b << 10) + m) * 3 + 1];
        bz[i] = wref[((b << 10) + m) * 3 + 2];
    }
    float cax = 0, cay = 0, caz = 0, cbx = 0, cby = 0, cbz = 0;
    #pragma unroll
    for (int i = 0; i < 4; ++i) {
        cax = fmaf(ax[i], w[i], cax); cay = fmaf(ay[i], w[i], cay); caz = fmaf(az[i], w[i], caz);
        cbx = fmaf(bx[i], w[i], cbx); cby = fmaf(by[i], w[i], cby); cbz = fmaf(bz[i], w[i], cbz);
    }
    cax = block_reduce_sum(cax, lds4, wv, lane);
    cay = block_reduce_sum(cay, lds4, wv, lane);
    caz = block_reduce_sum(caz, lds4, wv, lane);
    cbx = block_reduce_sum(cbx, lds4, wv, lane);
    cby = block_reduce_sum(cby, lds4, wv, lane);
    cbz = block_reduce_sum(cbz, lds4, wv, lane);
    float c[9] = {0,0,0,0,0,0,0,0,0};
    #pragma unroll
    for (int i = 0; i < 4; ++i) {
        const float dax = ax[i] - cax, day = ay[i] - cay, daz = az[i] - caz;
        const float dbx = (bx[i] - cbx) * w[i];
        const float dby = (by[i] - cby) * w[i];
        const float dbz = (bz[i] - cbz) * w[i];
        c[0] = fmaf(dax, dbx, c[0]); c[1] = fmaf(dax, dby, c[1]); c[2] = fmaf(dax, dbz, c[2]);
        c[3] = fmaf(day, dbx, c[3]); c[4] = fmaf(day, dby, c[4]); c[5] = fmaf(day, dbz, c[5]);
        c[6] = fmaf(daz, dbx, c[6]); c[7] = fmaf(daz, dby, c[7]); c[8] = fmaf(daz, dbz, c[8]);
    }
    #pragma unroll
    for (int k = 0; k < 9; ++k) c[k] = block_reduce_sum(c[k], lds4, wv, lane);
    if (tid == 0) {
        #pragma unroll
        for (int k = 0; k < 9; ++k) cov[b * 9 + k] = c[k];
        ca[b * 3 + 0] = cax; ca[b * 3 + 1] = cay; ca[b * 3 + 2] = caz;
        cb[b * 3 + 0] = cbx; cb[b * 3 + 1] = cby; cb[b * 3 + 2] = cbz;
    }
}

// ---------------------------------------------------------------------------
// Kernel 6: 3x3 SVD (double-precision Jacobi on A^T A) + Kabsch R,t
// one thread per batch — cost negligible, fp64 kills the eigen-solve error
// ---------------------------------------------------------------------------
__device__ __forceinline__ void jrot_d(double S[3][3], double V[3][3], int p, int q)
{
    const double apq = S[p][q];
    if (fabs(apq) < 1e-300) return;
    const double theta = (S[q][q] - S[p][p]) / (2.0 * apq);
    const double tt = copysign(1.0, theta) / (fabs(theta) + sqrt(1.0 + theta * theta));
    const double c = 1.0 / sqrt(1.0 + tt * tt);
    const double s = tt * c;
    #pragma unroll
    for (int k = 0; k < 3; ++k) {
        const double skp = S[k][p], skq = S[k][q];
        S[k][p] = c * skp - s * skq;
        S[k][q] = s * skp + c * skq;
    }
    #pragma unroll
    for (int k = 0; k < 3; ++k) {
        const double spk = S[p][k], sqk = S[q][k];
        S[p][k] = c * spk - s * sqk;
        S[q][k] = s * spk + c * sqk;
    }
    #pragma unroll
    for (int k = 0; k < 3; ++k) {
        const double vkp = V[k][p], vkq = V[k][q];
        V[k][p] = c * vkp - s * vkq;
        V[k][q] = s * vkp + c * vkq;
    }
}

__global__ __launch_bounds__(64)
void svd_kernel(const float* __restrict__ cov, const float* __restrict__ ca,
                const float* __restrict__ cb, float* __restrict__ out)
{
    const int b = threadIdx.x;
    if (b >= 32) return;
    double A[3][3];
    #pragma unroll
    for (int i = 0; i < 3; ++i)
        #pragma unroll
        for (int j = 0; j < 3; ++j)
            A[i][j] = (double)cov[b * 9 + i * 3 + j];
    // S = A^T A
    double S[3][3];
    #pragma unroll
    for (int i = 0; i < 3; ++i)
        #pragma unroll
        for (int j = 0; j < 3; ++j)
            S[i][j] = A[0][i] * A[0][j] + A[1][i] * A[1][j] + A[2][i] * A[2][j];
    double V[3][3] = {{1,0,0},{0,1,0},{0,0,1}};
    for (int sweep = 0; sweep < 8; ++sweep) {
        jrot_d(S, V, 0, 1);
        jrot_d(S, V, 0, 2);
        jrot_d(S, V, 1, 2);
    }
    // sort eigenvalues descending
    int o0 = 0, o1 = 1, o2 = 2;
    double e0 = S[0][0], e1 = S[1][1], e2 = S[2][2];
    double tf; int ti;
    if (e0 < e1) { tf = e0; e0 = e1; e1 = tf; ti = o0; o0 = o1; o1 = ti; }
    if (e0 < e2) { tf = e0; e0 = e2; e2 = tf; ti = o0; o0 = o2; o2 = ti; }
    if (e1 < e2) { tf = e1; e1 = e2; e2 = tf; ti = o1; o1 = o2; o2 = ti; }
    double v1[3] = {V[0][o0], V[1][o0], V[2][o0]};
    double v2[3] = {V[0][o1], V[1][o1], V[2][o1]};
    double v3[3] = {V[0][o2], V[1][o2], V[2][o2]};
    double Av1[3], Av2[3];
    #pragma unroll
    for (int i = 0; i < 3; ++i) {
        Av1[i] = A[i][0] * v1[0] + A[i][1] * v1[1] + A[i][2] * v1[2];
        Av2[i] = A[i][0] * v2[0] + A[i][1] * v2[1] + A[i][2] * v2[2];
    }
    const double n1 = sqrt(Av1[0]*Av1[0] + Av1[1]*Av1[1] + Av1[2]*Av1[2]);
    const double in1 = 1.0 / fmax(n1, 1e-300);
    double u1[3] = {Av1[0]*in1, Av1[1]*in1, Av1[2]*in1};
    const double d12 = Av2[0]*u1[0] + Av2[1]*u1[1] + Av2[2]*u1[2];
    double u2[3] = {Av2[0] - d12*u1[0], Av2[1] - d12*u1[1], Av2[2] - d12*u1[2]};
    const double n2 = sqrt(u2[0]*u2[0] + u2[1]*u2[1] + u2[2]*u2[2]);
    const double in2 = 1.0 / fmax(n2, 1e-300);
    u2[0] *= in2; u2[1] *= in2; u2[2] *= in2;
    double u3[3] = {u1[1]*u2[2] - u1[2]*u2[1],
                    u1[2]*u2[0] - u1[0]*u2[2],
                    u1[0]*u2[1] - u1[1]*u2[0]};
    double R0[3][3];
    #pragma unroll
    for (int i = 0; i < 3; ++i)
        #pragma unroll
        for (int j = 0; j < 3; ++j)
            R0[i][j] = v1[i]*u1[j] + v2[i]*u2[j] + v3[i]*u3[j];
    const double det =
        R0[0][0]*(R0[1][1]*R0[2][2] - R0[1][2]*R0[2][1])
      - R0[0][1]*(R0[1][0]*R0[2][2] - R0[1][2]*R0[2][0])
      + R0[0][2]*(R0[1][0]*R0[2][1] - R0[1][1]*R0[2][0]);
    double Rm[3][3];
    if (det > 0.0) {
        #pragma unroll
        for (int i = 0; i < 3; ++i)
            #pragma unroll
            for (int j = 0; j < 3; ++j)
                Rm[i][j] = R0[i][j];
    } else {
        #pragma unroll
        for (int i = 0; i < 3; ++i)
            #pragma unroll
            for (int j = 0; j < 3; ++j)
                Rm[i][j] = R0[i][j] - 2.0 * v3[i] * u3[j];
    }
    const double cax = (double)ca[b*3+0], cay = (double)ca[b*3+1], caz = (double)ca[b*3+2];
    #pragma unroll
    for (int i = 0; i < 3; ++i)
        #pragma unroll
        for (int j = 0; j < 3; ++j)
            out[b * 9 + i * 3 + j] = (float)Rm[i][j];
    #pragma unroll
    for (int i = 0; i < 3; ++i)
        out[288 + b * 3 + i] = (float)((double)cb[b*3+i] - (Rm[i][0]*cax + Rm[i][1]*cay + Rm[i][2]*caz));
}

// ---------------------------------------------------------------------------
extern "C" void kernel_launch(void* const* d_in, const int* in_sizes, int n_in,
                              void* d_out, int out_size, void* d_ws, size_t ws_size,
                              hipStream_t stream)
{
    const float* srcE = (const float*)d_in[0];   // (B,D,M)
    const float* tgtE = (const float*)d_in[1];   // (B,D,N)
    const float* src  = (const float*)d_in[2];   // (B,3,M)
    const float* tgt  = (const float*)d_in[3];   // (B,3,N)
    const float* lp   = (const float*)d_in[4];   // scalar l
    const float* rp   = (const float*)d_in[5];   // scalar rho
    float* out  = (float*)d_out;                 // R(288) | t(96) | P(32M)
    float* Pout = out + 384;                     // K lives here, overwritten by P

    float* ws   = (float*)d_ws;
    float* w1   = ws;            // 32768
    float* w2   = ws + 32768;    // 32768
    float* u    = ws + 65536;    // 32768
    float* v    = ws + 98304;    // 32768
    float* rowb = ws + 131072;   // 32768
    float* wref = ws + 163840;   // 98304
    float* part = ws + 262144;   // 262144 (8 x 32768)
    float* cov  = ws + 524288;   // 288
    float* ca   = ws + 524576;   // 96
    float* cb   = ws + 524672;   // 96

    norms_init_kernel<<<256, 256, 0, stream>>>(srcE, tgtE, w1, w2, v);
    gemm_kexp_kernel<<<dim3(8, 8, 32), 256, 0, stream>>>(srcE, tgtE, w1, w2, lp, Pout);
    for (int it = 0; it < 5; ++it) {
        u_update_kernel<<<8192, 256, 0, stream>>>(Pout, v, u, lp, rp);
        v_partial_kernel<<<dim3(4, 8, 32), 256, 0, stream>>>(Pout, u, part);
        v_finalize_kernel<<<128, 256, 0, stream>>>(part, v, lp, rp);
    }
    p_pass_kernel<<<8192, 256, 0, stream>>>(Pout, u, v, tgt, rowb, wref);
    kabsch_stats_kernel<<<32, 256, 0, stream>>>(rowb, wref, src, cov, ca, cb);
    svd_kernel<<<1, 64, 0, stream>>>(cov, ca, cb, out);
}

// Round 3
// 649.303 us; speedup vs baseline: 1.0197x; 1.0197x over previous
//
#include <hip/hip_runtime.h>
#include <math.h>

#define BB 32
#define DD 512
#define MM 1024
#define NN 1024

typedef float f32x4 __attribute__((ext_vector_type(4)));
typedef _Float16 f16x8 __attribute__((ext_vector_type(8)));

// ---------------------------------------------------------------------------
// Kernel 1: column norms of (B,D,M)/(B,D,N) embeddings + v init (v = 1/N)
// ---------------------------------------------------------------------------
__global__ __launch_bounds__(256)
void norms_init_kernel(const float* __restrict__ srcE, const float* __restrict__ tgtE,
                       float* __restrict__ w1, float* __restrict__ w2, float* __restrict__ v)
{
    const int idx = blockIdx.x * 256 + threadIdx.x;     // 0..65535
    const float* e; float* w; int r;
    if (idx < 32768) { e = srcE; w = w1; r = idx; v[idx] = 1.0f / 1024.0f; }
    else             { e = tgtE; w = w2; r = idx - 32768; }
    const int b = r >> 10;
    const int m = r & 1023;
    const float* p = e + (size_t)b * (DD * MM) + m;
    float acc = 0.f;
    #pragma unroll 8
    for (int d = 0; d < DD; ++d) {
        const float x = p[(size_t)d * MM];
        acc = fmaf(x, x, acc);
    }
    w[r] = sqrtf(acc);
}

// ---------------------------------------------------------------------------
// Kernel 2: fp16 MFMA GEMM (single pass; fp16 rounding -> ~2.7e-3 R error,
// calibrated from round-1 bf16 run which gave 2.17e-2 at 8x coarser ulp).
// Fused epilogue K = exp((sim-1)/l), fp32, into the P region of d_out.
// 128x128 tile, BK=64, XOR-swizzled LDS [row][k] (conflict-even b128 r/w).
// ---------------------------------------------------------------------------
__global__ __launch_bounds__(256, 4)
void gemm_kexp_kernel(const float* __restrict__ Ae, const float* __restrict__ Be,
                      const float* __restrict__ w1, const float* __restrict__ w2,
                      const float* __restrict__ lp, float* __restrict__ Kout)
{
    __shared__ _Float16 As[128 * 64];
    __shared__ _Float16 Bs[128 * 64];

    const int tid  = threadIdx.x;
    const int lane = tid & 63;
    const int wave = tid >> 6;
    const int m0 = blockIdx.x * 128;
    const int n0 = blockIdx.y * 128;
    const int b  = blockIdx.z;
    const int wm = (wave & 1) * 64;
    const int wn = (wave >> 1) * 64;
    const int m16  = lane & 15;
    const int quad = lane >> 4;

    const float* Ab = Ae + (size_t)b * DD * MM;
    const float* Bb = Be + (size_t)b * DD * NN;

    f32x4 acc[4][4];
    #pragma unroll
    for (int i = 0; i < 4; ++i)
        #pragma unroll
        for (int j = 0; j < 4; ++j)
            acc[i][j] = (f32x4){0.f, 0.f, 0.f, 0.f};

    const int sm = tid & 127;   // tile row (m or n) staged by this thread
    const int kh = tid >> 7;    // 0..1
    const int sw = sm & 7;      // xor swizzle key

    for (int kt = 0; kt < DD; kt += 64) {
        __syncthreads();
        // ---- stage: gather-transpose global (k-major) -> LDS fp16 ----
        #pragma unroll
        for (int t = 0; t < 4; ++t) {
            const int kg = kh + 2 * t;                       // 0..7 (8 k's each)
            const float* ap = Ab + (size_t)(kt + kg * 8) * MM + m0 + sm;
            const float* bp = Bb + (size_t)(kt + kg * 8) * NN + n0 + sm;
            float av[8], bv[8];
            #pragma unroll
            for (int j = 0; j < 8; ++j) av[j] = ap[(size_t)j * MM];
            #pragma unroll
            for (int j = 0; j < 8; ++j) bv[j] = bp[(size_t)j * NN];
            f16x8 pa, pb;
            #pragma unroll
            for (int j = 0; j < 8; ++j) { pa[j] = (_Float16)av[j]; pb[j] = (_Float16)bv[j]; }
            const int off = sm * 64 + ((kg ^ sw) << 3);
            *reinterpret_cast<f16x8*>(&As[off]) = pa;
            *reinterpret_cast<f16x8*>(&Bs[off]) = pb;
        }
        __syncthreads();
        // ---- compute: 2 k-steps of 32, 16 MFMAs each ----
        #pragma unroll
        for (int ks = 0; ks < 2; ++ks) {
            const int kg = ks * 4 + quad;
            f16x8 af[4], bfr[4];
            #pragma unroll
            for (int i = 0; i < 4; ++i) {
                const int rm = wm + i * 16 + m16;
                af[i]  = *reinterpret_cast<const f16x8*>(&As[rm * 64 + ((kg ^ (rm & 7)) << 3)]);
                const int rn = wn + i * 16 + m16;
                bfr[i] = *reinterpret_cast<const f16x8*>(&Bs[rn * 64 + ((kg ^ (rn & 7)) << 3)]);
            }
            #pragma unroll
            for (int i = 0; i < 4; ++i)
                #pragma unroll
                for (int j = 0; j < 4; ++j)
                    acc[i][j] = __builtin_amdgcn_mfma_f32_16x16x32_f16(af[i], bfr[j], acc[i][j], 0, 0, 0);
        }
    }

    // ---- epilogue: K = exp((dot/denom - 1) * 1/max(l,1e-8)) ----
    const float inv_l = 1.0f / fmaxf(lp[0], 1e-8f);
    float w2v[4];
    #pragma unroll
    for (int j = 0; j < 4; ++j) w2v[j] = w2[b * NN + n0 + wn + j * 16 + m16];
    float* Kb = Kout + ((size_t)b << 20);
    #pragma unroll
    for (int i = 0; i < 4; ++i) {
        #pragma unroll
        for (int r = 0; r < 4; ++r) {
            const int m = m0 + wm + i * 16 + quad * 4 + r;
            const float w1v = w1[b * MM + m];
            #pragma unroll
            for (int j = 0; j < 4; ++j) {
                const float dot = acc[i][j][r];
                const float den = fmaxf(w1v * w2v[j], 1e-6f);
                const float kv  = __expf((dot / den - 1.0f) * inv_l);
                Kb[(size_t)m * NN + (n0 + wn + j * 16 + m16)] = kv;
            }
        }
    }
}

// ---------------------------------------------------------------------------
// Kernel 3a (fused): one pass over K per Sinkhorn iteration.
// Per row m: s = K[m,:].v ; u_m = (a/clamp(s))^fi ; col_acc += u_m*K[m,:].
// grid (8 m-splits, 32 b); block 256 = 4 waves; wave covers 32 rows, whole row
// (1024 cols = 4 float4 per lane). Column partials reduced across waves in LDS,
// written to part[(ms*32+b)*1024 + col]; v_finalize sums the 8 m-splits.
// ---------------------------------------------------------------------------
__global__ __launch_bounds__(256)
void uv_fused_kernel(const float* __restrict__ Kmat, const float* __restrict__ v,
                     float* __restrict__ u, float* __restrict__ part,
                     const float* __restrict__ lp, const float* __restrict__ rp)
{
    const int ms = blockIdx.x;          // 0..7
    const int b  = blockIdx.y;          // 0..31
    const int wv = threadIdx.x >> 6, lane = threadIdx.x & 63;
    const float l = lp[0], rho = rp[0];
    const float fi = rho / fmaxf(rho + l, 1e-8f);

    const float4* vb = reinterpret_cast<const float4*>(v + (b << 10));
    float4 vreg[4];
    #pragma unroll
    for (int c = 0; c < 4; ++c) vreg[c] = vb[c * 64 + lane];

    float4 cacc[4];
    #pragma unroll
    for (int c = 0; c < 4; ++c) cacc[c] = (float4){0.f, 0.f, 0.f, 0.f};

    const int m0 = ms * 128 + wv * 32;
    const float4* Kb = reinterpret_cast<const float4*>(Kmat + ((size_t)b << 20));
    float* ub = u + (b << 10);

    for (int mm = 0; mm < 32; ++mm) {
        const int m = m0 + mm;
        const float4* row = Kb + (size_t)m * 256;
        float4 k4[4];
        #pragma unroll
        for (int c = 0; c < 4; ++c) k4[c] = row[c * 64 + lane];
        float s = 0.f;
        #pragma unroll
        for (int c = 0; c < 4; ++c) {
            s = fmaf(k4[c].x, vreg[c].x, s);
            s = fmaf(k4[c].y, vreg[c].y, s);
            s = fmaf(k4[c].z, vreg[c].z, s);
            s = fmaf(k4[c].w, vreg[c].w, s);
        }
        #pragma unroll
        for (int off = 32; off > 0; off >>= 1) s += __shfl_down(s, off);
        s = __builtin_amdgcn_readfirstlane(s);
        const float um = __powf((1.0f / 1024.0f) / fmaxf(s, 1e-8f), fi);
        if (lane == 0) ub[m] = um;
        #pragma unroll
        for (int c = 0; c < 4; ++c) {
            cacc[c].x = fmaf(k4[c].x, um, cacc[c].x);
            cacc[c].y = fmaf(k4[c].y, um, cacc[c].y);
            cacc[c].z = fmaf(k4[c].z, um, cacc[c].z);
            cacc[c].w = fmaf(k4[c].w, um, cacc[c].w);
        }
    }

    __shared__ float4 red[4][256];
    #pragma unroll
    for (int c = 0; c < 4; ++c) red[wv][c * 64 + lane] = cacc[c];
    __syncthreads();
    const int t = threadIdx.x;
    float4 s4 = red[0][t];
    #pragma unroll
    for (int w = 1; w < 4; ++w) {
        s4.x += red[w][t].x; s4.y += red[w][t].y;
        s4.z += red[w][t].z; s4.w += red[w][t].w;
    }
    reinterpret_cast<float4*>(part)[(ms * 32 + b) * 256 + t] = s4;
}

// ---------------------------------------------------------------------------
// Kernel 3b: v = (b / clamp(sum partials, 1e-8))^fi
// ---------------------------------------------------------------------------
__global__ __launch_bounds__(256)
void v_finalize_kernel(const float* __restrict__ part, float* __restrict__ v,
                       const float* __restrict__ lp, const float* __restrict__ rp)
{
    const int idx = blockIdx.x * 256 + threadIdx.x;   // 0..32767 = b*1024+n
    float s = 0.f;
    #pragma unroll
    for (int ms = 0; ms < 8; ++ms) s += part[ms * 32768 + idx];
    const float l = lp[0], rho = rp[0];
    const float fi = rho / fmaxf(rho + l, 1e-8f);
    v[idx] = __powf((1.0f / 1024.0f) / fmaxf(s, 1e-8f), fi);
}

// ---------------------------------------------------------------------------
// Kernel 4: P = u*K*v (in-place over K), row sums, weighted_ref
// one wave per row
// ---------------------------------------------------------------------------
__global__ __launch_bounds__(256)
void p_pass_kernel(float* __restrict__ Kmat, const float* __restrict__ u,
                   const float* __restrict__ v, const float* __restrict__ tgt,
                   float* __restrict__ rowb, float* __restrict__ wref)
{
    const int gid  = (blockIdx.x * 256 + threadIdx.x) >> 6;
    const int lane = threadIdx.x & 63;
    const int b = gid >> 10;
    float4* row = reinterpret_cast<float4*>(Kmat + ((size_t)gid << 10));
    const float4* vb = reinterpret_cast<const float4*>(v + (b << 10));
    const float4* tb = reinterpret_cast<const float4*>(tgt + (size_t)b * 3072);
    const float um = u[gid];
    float4 s4 = {0,0,0,0}, x4 = {0,0,0,0}, y4 = {0,0,0,0}, z4 = {0,0,0,0};
    #pragma unroll
    for (int it = 0; it < 4; ++it) {
        const int i = it * 64 + lane;
        const float4 k4 = row[i];
        const float4 v4 = vb[i];
        float4 p;
        p.x = um * k4.x * v4.x;
        p.y = um * k4.y * v4.y;
        p.z = um * k4.z * v4.z;
        p.w = um * k4.w * v4.w;
        row[i] = p;
        const float4 tx = tb[i], ty = tb[256 + i], tz = tb[512 + i];
        s4.x += p.x; s4.y += p.y; s4.z += p.z; s4.w += p.w;
        x4.x = fmaf(p.x, tx.x, x4.x); x4.y = fmaf(p.y, tx.y, x4.y);
        x4.z = fmaf(p.z, tx.z, x4.z); x4.w = fmaf(p.w, tx.w, x4.w);
        y4.x = fmaf(p.x, ty.x, y4.x); y4.y = fmaf(p.y, ty.y, y4.y);
        y4.z = fmaf(p.z, ty.z, y4.z); y4.w = fmaf(p.w, ty.w, y4.w);
        z4.x = fmaf(p.x, tz.x, z4.x); z4.y = fmaf(p.y, tz.y, z4.y);
        z4.z = fmaf(p.z, tz.z, z4.z); z4.w = fmaf(p.w, tz.w, z4.w);
    }
    float s = (s4.x + s4.y) + (s4.z + s4.w);
    float x = (x4.x + x4.y) + (x4.z + x4.w);
    float y = (y4.x + y4.y) + (y4.z + y4.w);
    float z = (z4.x + z4.y) + (z4.z + z4.w);
    #pragma unroll
    for (int off = 32; off > 0; off >>= 1) {
        s += __shfl_down(s, off);
        x += __shfl_down(x, off);
        y += __shfl_down(y, off);
        z += __shfl_down(z, off);
    }
    if (lane == 0) {
        rowb[gid] = s;
        const float inv = 1.0f / (s + 1e-6f);
        wref[gid * 3 + 0] = x * inv;
        wref[gid * 3 + 1] = y * inv;
        wref[gid * 3 + 2] = z * inv;
    }
}

// ---------------------------------------------------------------------------
// Kernel 5: per-batch weighted centroids + covariance (one block per batch)
// ---------------------------------------------------------------------------
__device__ __forceinline__ float block_reduce_sum(float x, float* lds4, int wv, int lane)
{
    #pragma unroll
    for (int off = 32; off > 0; off >>= 1) x += __shfl_down(x, off);
    __syncthreads();
    if (lane == 0) lds4[wv] = x;
    __syncthreads();
    return (lds4[0] + lds4[1]) + (lds4[2] + lds4[3]);
}

__global__ __launch_bounds__(256)
void kabsch_stats_kernel(const float* __restrict__ rowb, const float* __restrict__ wref,
                         const float* __restrict__ src, float* __restrict__ cov,
                         float* __restrict__ ca, float* __restrict__ cb)
{
    __shared__ float lds4[4];
    const int b = blockIdx.x, tid = threadIdx.x;
    const int wv = tid >> 6, lane = tid & 63;
    float r[4], w[4], ax[4], ay[4], az[4], bx[4], by[4], bz[4];
    float rsum = 0.f;
    #pragma unroll
    for (int i = 0; i < 4; ++i) {
        const int m = tid + 256 * i;
        r[i] = rowb[(b << 10) + m];
        rsum += r[i];
    }
    const float total = block_reduce_sum(rsum, lds4, wv, lane);
    const float inv = 1.0f / (total + 1e-6f);
    #pragma unroll
    for (int i = 0; i < 4; ++i) {
        const int m = tid + 256 * i;
        w[i]  = r[i] * inv;
        ax[i] = src[b * 3072 + m];
        ay[i] = src[b * 3072 + 1024 + m];
        az[i] = src[b * 3072 + 2048 + m];
        bx[i] = wref[((b << 10) + m) * 3 + 0];
        by[i] = wref[((b << 10) + m) * 3 + 1];
        bz[i] = wref[((b << 10) + m) * 3 + 2];
    }
    float cax = 0, cay = 0, caz = 0, cbx = 0, cby = 0, cbz = 0;
    #pragma unroll
    for (int i = 0; i < 4; ++i) {
        cax = fmaf(ax[i], w[i], cax); cay = fmaf(ay[i], w[i], cay); caz = fmaf(az[i], w[i], caz);
        cbx = fmaf(bx[i], w[i], cbx); cby = fmaf(by[i], w[i], cby); cbz = fmaf(bz[i], w[i], cbz);
    }
    cax = block_reduce_sum(cax, lds4, wv, lane);
    cay = block_reduce_sum(cay, lds4, wv, lane);
    caz = block_reduce_sum(caz, lds4, wv, lane);
    cbx = block_reduce_sum(cbx, lds4, wv, lane);
    cby = block_reduce_sum(cby, lds4, wv, lane);
    cbz = block_reduce_sum(cbz, lds4, wv, lane);
    float c[9] = {0,0,0,0,0,0,0,0,0};
    #pragma unroll
    for (int i = 0; i < 4; ++i) {
        const float dax = ax[i] - cax, day = ay[i] - cay, daz = az[i] - caz;
        const float dbx = (bx[i] - cbx) * w[i];
        const float dby = (by[i] - cby) * w[i];
        const float dbz = (bz[i] - cbz) * w[i];
        c[0] = fmaf(dax, dbx, c[0]); c[1] = fmaf(dax, dby, c[1]); c[2] = fmaf(dax, dbz, c[2]);
        c[3] = fmaf(day, dbx, c[3]); c[4] = fmaf(day, dby, c[4]); c[5] = fmaf(day, dbz, c[5]);
        c[6] = fmaf(daz, dbx, c[6]); c[7] = fmaf(daz, dby, c[7]); c[8] = fmaf(daz, dbz, c[8]);
    }
    #pragma unroll
    for (int k = 0; k < 9; ++k) c[k] = block_reduce_sum(c[k], lds4, wv, lane);
    if (tid == 0) {
        #pragma unroll
        for (int k = 0; k < 9; ++k) cov[b * 9 + k] = c[k];
        ca[b * 3 + 0] = cax; ca[b * 3 + 1] = cay; ca[b * 3 + 2] = caz;
        cb[b * 3 + 0] = cbx; cb[b * 3 + 1] = cby; cb[b * 3 + 2] = cbz;
    }
}

// ---------------------------------------------------------------------------
// Kernel 6: 3x3 SVD (double-precision Jacobi on A^T A) + Kabsch R,t
// one thread per batch — cost negligible, fp64 kills the eigen-solve error
// ---------------------------------------------------------------------------
__device__ __forceinline__ void jrot_d(double S[3][3], double V[3][3], int p, int q)
{
    const double apq = S[p][q];
    if (fabs(apq) < 1e-300) return;
    const double theta = (S[q][q] - S[p][p]) / (2.0 * apq);
    const double tt = copysign(1.0, theta) / (fabs(theta) + sqrt(1.0 + theta * theta));
    const double c = 1.0 / sqrt(1.0 + tt * tt);
    const double s = tt * c;
    #pragma unroll
    for (int k = 0; k < 3; ++k) {
        const double skp = S[k][p], skq = S[k][q];
        S[k][p] = c * skp - s * skq;
        S[k][q] = s * skp + c * skq;
    }
    #pragma unroll
    for (int k = 0; k < 3; ++k) {
        const double spk = S[p][k], sqk = S[q][k];
        S[p][k] = c * spk - s * sqk;
        S[q][k] = s * spk + c * sqk;
    }
    #pragma unroll
    for (int k = 0; k < 3; ++k) {
        const double vkp = V[k][p], vkq = V[k][q];
        V[k][p] = c * vkp - s * vkq;
        V[k][q] = s * vkp + c * vkq;
    }
}

__global__ __launch_bounds__(64)
void svd_kernel(const float* __restrict__ cov, const float* __restrict__ ca,
                const float* __restrict__ cb, float* __restrict__ out)
{
    const int b = threadIdx.x;
    if (b >= 32) return;
    double A[3][3];
    #pragma unroll
    for (int i = 0; i < 3; ++i)
        #pragma unroll
        for (int j = 0; j < 3; ++j)
            A[i][j] = (double)cov[b * 9 + i * 3 + j];
    // S = A^T A
    double S[3][3];
    #pragma unroll
    for (int i = 0; i < 3; ++i)
        #pragma unroll
        for (int j = 0; j < 3; ++j)
            S[i][j] = A[0][i] * A[0][j] + A[1][i] * A[1][j] + A[2][i] * A[2][j];
    double V[3][3] = {{1,0,0},{0,1,0},{0,0,1}};
    for (int sweep = 0; sweep < 8; ++sweep) {
        jrot_d(S, V, 0, 1);
        jrot_d(S, V, 0, 2);
        jrot_d(S, V, 1, 2);
    }
    // sort eigenvalues descending
    int o0 = 0, o1 = 1, o2 = 2;
    double e0 = S[0][0], e1 = S[1][1], e2 = S[2][2];
    double tf; int ti;
    if (e0 < e1) { tf = e0; e0 = e1; e1 = tf; ti = o0; o0 = o1; o1 = ti; }
    if (e0 < e2) { tf = e0; e0 = e2; e2 = tf; ti = o0; o0 = o2; o2 = ti; }
    if (e1 < e2) { tf = e1; e1 = e2; e2 = tf; ti = o1; o1 = o2; o2 = ti; }
    double v1[3] = {V[0][o0], V[1][o0], V[2][o0]};
    double v2[3] = {V[0][o1], V[1][o1], V[2][o1]};
    double v3[3] = {V[0][o2], V[1][o2], V[2][o2]};
    double Av1[3], Av2[3];
    #pragma unroll
    for (int i = 0; i < 3; ++i) {
        Av1[i] = A[i][0] * v1[0] + A[i][1] * v1[1] + A[i][2] * v1[2];
        Av2[i] = A[i][0] * v2[0] + A[i][1] * v2[1] + A[i][2] * v2[2];
    }
    const double n1 = sqrt(Av1[0]*Av1[0] + Av1[1]*Av1[1] + Av1[2]*Av1[2]);
    const double in1 = 1.0 / fmax(n1, 1e-300);
    double u1[3] = {Av1[0]*in1, Av1[1]*in1, Av1[2]*in1};
    const double d12 = Av2[0]*u1[0] + Av2[1]*u1[1] + Av2[2]*u1[2];
    double u2[3] = {Av2[0] - d12*u1[0], Av2[1] - d12*u1[1], Av2[2] - d12*u1[2]};
    const double n2 = sqrt(u2[0]*u2[0] + u2[1]*u2[1] + u2[2]*u2[2]);
    const double in2 = 1.0 / fmax(n2, 1e-300);
    u2[0] *= in2; u2[1] *= in2; u2[2] *= in2;
    double u3[3] = {u1[1]*u2[2] - u1[2]*u2[1],
                    u1[2]*u2[0] - u1[0]*u2[2],
                    u1[0]*u2[1] - u1[1]*u2[0]};
    double R0[3][3];
    #pragma unroll
    for (int i = 0; i < 3; ++i)
        #pragma unroll
        for (int j = 0; j < 3; ++j)
            R0[i][j] = v1[i]*u1[j] + v2[i]*u2[j] + v3[i]*u3[j];
    const double det =
        R0[0][0]*(R0[1][1]*R0[2][2] - R0[1][2]*R0[2][1])
      - R0[0][1]*(R0[1][0]*R0[2][2] - R0[1][2]*R0[2][0])
      + R0[0][2]*(R0[1][0]*R0[2][1] - R0[1][1]*R0[2][0]);
    double Rm[3][3];
    if (det > 0.0) {
        #pragma unroll
        for (int i = 0; i < 3; ++i)
            #pragma unroll
            for (int j = 0; j < 3; ++j)
                Rm[i][j] = R0[i][j];
    } else {
        #pragma unroll
        for (int i = 0; i < 3; ++i)
            #pragma unroll
            for (int j = 0; j < 3; ++j)
                Rm[i][j] = R0[i][j] - 2.0 * v3[i] * u3[j];
    }
    const double cax = (double)ca[b*3+0], cay = (double)ca[b*3+1], caz = (double)ca[b*3+2];
    #pragma unroll
    for (int i = 0; i < 3; ++i)
        #pragma unroll
        for (int j = 0; j < 3; ++j)
            out[b * 9 + i * 3 + j] = (float)Rm[i][j];
    #pragma unroll
    for (int i = 0; i < 3; ++i)
        out[288 + b * 3 + i] = (float)((double)cb[b*3+i] - (Rm[i][0]*cax + Rm[i][1]*cay + Rm[i][2]*caz));
}

// ---------------------------------------------------------------------------
extern "C" void kernel_launch(void* const* d_in, const int* in_sizes, int n_in,
                              void* d_out, int out_size, void* d_ws, size_t ws_size,
                              hipStream_t stream)
{
    const float* srcE = (const float*)d_in[0];   // (B,D,M)
    const float* tgtE = (const float*)d_in[1];   // (B,D,N)
    const float* src  = (const float*)d_in[2];   // (B,3,M)
    const float* tgt  = (const float*)d_in[3];   // (B,3,N)
    const float* lp   = (const float*)d_in[4];   // scalar l
    const float* rp   = (const float*)d_in[5];   // scalar rho
    float* out  = (float*)d_out;                 // R(288) | t(96) | P(32M)
    float* Pout = out + 384;                     // K lives here, overwritten by P

    float* ws   = (float*)d_ws;
    float* w1   = ws;            // 32768
    float* w2   = ws + 32768;    // 32768
    float* u    = ws + 65536;    // 32768
    float* v    = ws + 98304;    // 32768
    float* rowb = ws + 131072;   // 32768
    float* wref = ws + 163840;   // 98304
    float* part = ws + 262144;   // 262144 (8 x 32768)
    float* cov  = ws + 524288;   // 288
    float* ca   = ws + 524576;   // 96
    float* cb   = ws + 524672;   // 96

    norms_init_kernel<<<256, 256, 0, stream>>>(srcE, tgtE, w1, w2, v);
    gemm_kexp_kernel<<<dim3(8, 8, 32), 256, 0, stream>>>(srcE, tgtE, w1, w2, lp, Pout);
    for (int it = 0; it < 5; ++it) {
        uv_fused_kernel<<<dim3(8, 32), 256, 0, stream>>>(Pout, v, u, part, lp, rp);
        v_finalize_kernel<<<128, 256, 0, stream>>>(part, v, lp, rp);
    }
    p_pass_kernel<<<8192, 256, 0, stream>>>(Pout, u, v, tgt, rowb, wref);
    kabsch_stats_kernel<<<32, 256, 0, stream>>>(rowb, wref, src, cov, ca, cb);
    svd_kernel<<<1, 64, 0, stream>>>(cov, ca, cb, out);
}

// Round 4
// 574.893 us; speedup vs baseline: 1.1517x; 1.1294x over previous
//
#include <hip/hip_runtime.h>
#include <math.h>

#define BB 32
#define DD 512
#define MM 1024
#define NN 1024

typedef float f32x4 __attribute__((ext_vector_type(4)));
typedef _Float16 f16x8 __attribute__((ext_vector_type(8)));

// ---------------------------------------------------------------------------
// Kernel 1: column norms of embeddings + v init (v = 1/N) + colsum zero
// ---------------------------------------------------------------------------
__global__ __launch_bounds__(256)
void norms_init_kernel(const float* __restrict__ srcE, const float* __restrict__ tgtE,
                       float* __restrict__ w1, float* __restrict__ w2,
                       float* __restrict__ v, float* __restrict__ colsum)
{
    const int idx = blockIdx.x * 256 + threadIdx.x;     // 0..65535
    const float* e; float* w; int r;
    if (idx < 32768) {
        e = srcE; w = w1; r = idx;
        v[idx] = 1.0f / 1024.0f;
        colsum[idx] = 0.0f;          // ws is poisoned 0xAA each call
    } else {
        e = tgtE; w = w2; r = idx - 32768;
    }
    const int b = r >> 10;
    const int m = r & 1023;
    const float* p = e + (size_t)b * (DD * MM) + m;
    float acc = 0.f;
    #pragma unroll 8
    for (int d = 0; d < DD; ++d) {
        const float x = p[(size_t)d * MM];
        acc = fmaf(x, x, acc);
    }
    w[r] = sqrtf(acc);
}

// ---------------------------------------------------------------------------
// Kernel 2: fp16 MFMA GEMM with register-prefetch software pipeline.
// Tile t+1's global loads are issued before tile t's MFMA phase so their
// latency hides behind compute (the 2-barrier structure otherwise exposes it:
// R3 showed MfmaUtil 8% / VALUBusy 20% / HBM 32% -> latency-bound).
// Fused epilogue K = exp((sim-1)/l), fp32, into the P region of d_out.
// 128x128 tile, BK=64, XOR-swizzled LDS [row][k] (conflict-even b128 r/w).
// ---------------------------------------------------------------------------
__global__ __launch_bounds__(256)
void gemm_kexp_kernel(const float* __restrict__ Ae, const float* __restrict__ Be,
                      const float* __restrict__ w1, const float* __restrict__ w2,
                      const float* __restrict__ lp, float* __restrict__ Kout)
{
    __shared__ _Float16 As[128 * 64];
    __shared__ _Float16 Bs[128 * 64];

    const int tid  = threadIdx.x;
    const int lane = tid & 63;
    const int wave = tid >> 6;
    const int m0 = blockIdx.x * 128;
    const int n0 = blockIdx.y * 128;
    const int b  = blockIdx.z;
    const int wm = (wave & 1) * 64;
    const int wn = (wave >> 1) * 64;
    const int m16  = lane & 15;
    const int quad = lane >> 4;

    const float* Ab = Ae + (size_t)b * DD * MM;
    const float* Bb = Be + (size_t)b * DD * NN;

    f32x4 acc[4][4];
    #pragma unroll
    for (int i = 0; i < 4; ++i)
        #pragma unroll
        for (int j = 0; j < 4; ++j)
            acc[i][j] = (f32x4){0.f, 0.f, 0.f, 0.f};

    const int sm = tid & 127;   // tile row (m or n) staged by this thread
    const int kh = tid >> 7;    // 0..1
    const int sw = sm & 7;      // xor swizzle key
    const float* apBase = Ab + m0 + sm;
    const float* bpBase = Bb + n0 + sm;

    float av[4][8], bv[4][8];
    // ---- prologue: issue loads for k-tile 0 ----
    #pragma unroll
    for (int t = 0; t < 4; ++t) {
        const int kg = kh + 2 * t;
        const float* ap = apBase + (size_t)(kg * 8) * MM;
        const float* bp = bpBase + (size_t)(kg * 8) * NN;
        #pragma unroll
        for (int j = 0; j < 8; ++j) { av[t][j] = ap[(size_t)j * MM]; bv[t][j] = bp[(size_t)j * NN]; }
    }

    for (int kt = 0; kt < 8; ++kt) {
        // ---- convert current tile (waits on its loads) ----
        f16x8 pa[4], pb[4];
        #pragma unroll
        for (int t = 0; t < 4; ++t)
            #pragma unroll
            for (int j = 0; j < 8; ++j) { pa[t][j] = (_Float16)av[t][j]; pb[t][j] = (_Float16)bv[t][j]; }
        if (kt) __syncthreads();             // previous MFMA phase done with LDS
        #pragma unroll
        for (int t = 0; t < 4; ++t) {
            const int kg = kh + 2 * t;
            const int off = sm * 64 + ((kg ^ sw) << 3);
            *reinterpret_cast<f16x8*>(&As[off]) = pa[t];
            *reinterpret_cast<f16x8*>(&Bs[off]) = pb[t];
        }
        __syncthreads();
        // ---- issue next tile's loads; latency hides behind MFMA phase ----
        if (kt < 7) {
            const size_t kbase = (size_t)(kt + 1) * 64;
            #pragma unroll
            for (int t = 0; t < 4; ++t) {
                const int kg = kh + 2 * t;
                const float* ap = apBase + (kbase + kg * 8) * MM;
                const float* bp = bpBase + (kbase + kg * 8) * NN;
                #pragma unroll
                for (int j = 0; j < 8; ++j) { av[t][j] = ap[(size_t)j * MM]; bv[t][j] = bp[(size_t)j * NN]; }
            }
        }
        // ---- compute: 2 k-steps of 32, 16 MFMAs each ----
        #pragma unroll
        for (int ks = 0; ks < 2; ++ks) {
            const int kg = ks * 4 + quad;
            f16x8 af[4], bfr[4];
            #pragma unroll
            for (int i = 0; i < 4; ++i) {
                const int rm = wm + i * 16 + m16;
                af[i]  = *reinterpret_cast<const f16x8*>(&As[rm * 64 + ((kg ^ (rm & 7)) << 3)]);
                const int rn = wn + i * 16 + m16;
                bfr[i] = *reinterpret_cast<const f16x8*>(&Bs[rn * 64 + ((kg ^ (rn & 7)) << 3)]);
            }
            #pragma unroll
            for (int i = 0; i < 4; ++i)
                #pragma unroll
                for (int j = 0; j < 4; ++j)
                    acc[i][j] = __builtin_amdgcn_mfma_f32_16x16x32_f16(af[i], bfr[j], acc[i][j], 0, 0, 0);
        }
    }

    // ---- epilogue: K = exp((dot/denom - 1) * 1/max(l,1e-8)) ----
    const float inv_l = 1.0f / fmaxf(lp[0], 1e-8f);
    float w2v[4];
    #pragma unroll
    for (int j = 0; j < 4; ++j) w2v[j] = w2[b * NN + n0 + wn + j * 16 + m16];
    float* Kb = Kout + ((size_t)b << 20);
    #pragma unroll
    for (int i = 0; i < 4; ++i) {
        #pragma unroll
        for (int r = 0; r < 4; ++r) {
            const int m = m0 + wm + i * 16 + quad * 4 + r;
            const float w1v = w1[b * MM + m];
            #pragma unroll
            for (int j = 0; j < 4; ++j) {
                const float dot = acc[i][j][r];
                const float den = fmaxf(w1v * w2v[j], 1e-6f);
                const float kv  = __expf((dot / den - 1.0f) * inv_l);
                Kb[(size_t)m * NN + (n0 + wn + j * 16 + m16)] = kv;
            }
        }
    }
}

// ---------------------------------------------------------------------------
// Kernel 3a (fused): one pass over K per Sinkhorn iteration.
// grid (32 ms, 32 b) = 1024 blocks (4/CU); wave handles 8 rows in 2 groups
// of 4 (batched loads, 4-wide-ILP shuffle reduces). Column partials: LDS
// cross-wave reduce then atomicAdd into colsum (zeroed by v_finalize for the
// next iteration; initially by norms_init).
// ---------------------------------------------------------------------------
__global__ __launch_bounds__(256)
void uv_fused_kernel(const float* __restrict__ Kmat, const float* __restrict__ v,
                     float* __restrict__ u, float* __restrict__ colsum,
                     const float* __restrict__ lp, const float* __restrict__ rp)
{
    const int ms = blockIdx.x;          // 0..31
    const int b  = blockIdx.y;          // 0..31
    const int wv = threadIdx.x >> 6, lane = threadIdx.x & 63;
    const float l = lp[0], rho = rp[0];
    const float fi = rho / fmaxf(rho + l, 1e-8f);

    const float4* vb = reinterpret_cast<const float4*>(v + (b << 10));
    float4 vreg[4];
    #pragma unroll
    for (int c = 0; c < 4; ++c) vreg[c] = vb[c * 64 + lane];

    float4 cacc[4];
    #pragma unroll
    for (int c = 0; c < 4; ++c) cacc[c] = (float4){0.f, 0.f, 0.f, 0.f};

    const int m0 = ms * 32 + wv * 8;
    const float4* Kb = reinterpret_cast<const float4*>(Kmat + ((size_t)b << 20));
    float* ub = u + (b << 10);

    #pragma unroll
    for (int g = 0; g < 2; ++g) {
        float4 k4[4][4];                 // [row][colchunk]
        #pragma unroll
        for (int r = 0; r < 4; ++r) {
            const int m = m0 + g * 4 + r;
            const float4* row = Kb + (size_t)m * 256;
            #pragma unroll
            for (int c = 0; c < 4; ++c) k4[r][c] = row[c * 64 + lane];
        }
        float s[4];
        #pragma unroll
        for (int r = 0; r < 4; ++r) {
            float t = 0.f;
            #pragma unroll
            for (int c = 0; c < 4; ++c) {
                t = fmaf(k4[r][c].x, vreg[c].x, t);
                t = fmaf(k4[r][c].y, vreg[c].y, t);
                t = fmaf(k4[r][c].z, vreg[c].z, t);
                t = fmaf(k4[r][c].w, vreg[c].w, t);
            }
            s[r] = t;
        }
        #pragma unroll
        for (int off = 32; off > 0; off >>= 1)
            #pragma unroll
            for (int r = 0; r < 4; ++r) s[r] += __shfl_down(s[r], off);
        float um[4];
        #pragma unroll
        for (int r = 0; r < 4; ++r) {
            const float sv = __builtin_amdgcn_readfirstlane(s[r]);
            um[r] = __powf((1.0f / 1024.0f) / fmaxf(sv, 1e-8f), fi);
        }
        if (lane == 0) {
            #pragma unroll
            for (int r = 0; r < 4; ++r) ub[m0 + g * 4 + r] = um[r];
        }
        #pragma unroll
        for (int r = 0; r < 4; ++r)
            #pragma unroll
            for (int c = 0; c < 4; ++c) {
                cacc[c].x = fmaf(k4[r][c].x, um[r], cacc[c].x);
                cacc[c].y = fmaf(k4[r][c].y, um[r], cacc[c].y);
                cacc[c].z = fmaf(k4[r][c].z, um[r], cacc[c].z);
                cacc[c].w = fmaf(k4[r][c].w, um[r], cacc[c].w);
            }
    }

    __shared__ float4 red[4][256];
    #pragma unroll
    for (int c = 0; c < 4; ++c) red[wv][c * 64 + lane] = cacc[c];
    __syncthreads();
    const int t = threadIdx.x;
    float4 s4 = red[0][t];
    #pragma unroll
    for (int w = 1; w < 4; ++w) {
        s4.x += red[w][t].x; s4.y += red[w][t].y;
        s4.z += red[w][t].z; s4.w += red[w][t].w;
    }
    float* cs = colsum + (b << 10) + t * 4;
    atomicAdd(cs + 0, s4.x);
    atomicAdd(cs + 1, s4.y);
    atomicAdd(cs + 2, s4.z);
    atomicAdd(cs + 3, s4.w);
}

// ---------------------------------------------------------------------------
// Kernel 3b: v = (b / clamp(colsum, 1e-8))^fi ; re-zero colsum for next iter
// ---------------------------------------------------------------------------
__global__ __launch_bounds__(256)
void v_finalize_kernel(float* __restrict__ colsum, float* __restrict__ v,
                       const float* __restrict__ lp, const float* __restrict__ rp)
{
    const int idx = blockIdx.x * 256 + threadIdx.x;   // 0..32767 = b*1024+n
    const float s = colsum[idx];
    colsum[idx] = 0.0f;
    const float l = lp[0], rho = rp[0];
    const float fi = rho / fmaxf(rho + l, 1e-8f);
    v[idx] = __powf((1.0f / 1024.0f) / fmaxf(s, 1e-8f), fi);
}

// ---------------------------------------------------------------------------
// Kernel 4: P = u*K*v (in-place over K), row sums, weighted_ref
// one wave per row
// ---------------------------------------------------------------------------
__global__ __launch_bounds__(256)
void p_pass_kernel(float* __restrict__ Kmat, const float* __restrict__ u,
                   const float* __restrict__ v, const float* __restrict__ tgt,
                   float* __restrict__ rowb, float* __restrict__ wref)
{
    const int gid  = (blockIdx.x * 256 + threadIdx.x) >> 6;
    const int lane = threadIdx.x & 63;
    const int b = gid >> 10;
    float4* row = reinterpret_cast<float4*>(Kmat + ((size_t)gid << 10));
    const float4* vb = reinterpret_cast<const float4*>(v + (b << 10));
    const float4* tb = reinterpret_cast<const float4*>(tgt + (size_t)b * 3072);
    const float um = u[gid];
    float4 s4 = {0,0,0,0}, x4 = {0,0,0,0}, y4 = {0,0,0,0}, z4 = {0,0,0,0};
    #pragma unroll
    for (int it = 0; it < 4; ++it) {
        const int i = it * 64 + lane;
        const float4 k4 = row[i];
        const float4 v4 = vb[i];
        float4 p;
        p.x = um * k4.x * v4.x;
        p.y = um * k4.y * v4.y;
        p.z = um * k4.z * v4.z;
        p.w = um * k4.w * v4.w;
        row[i] = p;
        const float4 tx = tb[i], ty = tb[256 + i], tz = tb[512 + i];
        s4.x += p.x; s4.y += p.y; s4.z += p.z; s4.w += p.w;
        x4.x = fmaf(p.x, tx.x, x4.x); x4.y = fmaf(p.y, tx.y, x4.y);
        x4.z = fmaf(p.z, tx.z, x4.z); x4.w = fmaf(p.w, tx.w, x4.w);
        y4.x = fmaf(p.x, ty.x, y4.x); y4.y = fmaf(p.y, ty.y, y4.y);
        y4.z = fmaf(p.z, ty.z, y4.z); y4.w = fmaf(p.w, ty.w, y4.w);
        z4.x = fmaf(p.x, tz.x, z4.x); z4.y = fmaf(p.y, tz.y, z4.y);
        z4.z = fmaf(p.z, tz.z, z4.z); z4.w = fmaf(p.w, tz.w, z4.w);
    }
    float s = (s4.x + s4.y) + (s4.z + s4.w);
    float x = (x4.x + x4.y) + (x4.z + x4.w);
    float y = (y4.x + y4.y) + (y4.z + y4.w);
    float z = (z4.x + z4.y) + (z4.z + z4.w);
    #pragma unroll
    for (int off = 32; off > 0; off >>= 1) {
        s += __shfl_down(s, off);
        x += __shfl_down(x, off);
        y += __shfl_down(y, off);
        z += __shfl_down(z, off);
    }
    if (lane == 0) {
        rowb[gid] = s;
        const float inv = 1.0f / (s + 1e-6f);
        wref[gid * 3 + 0] = x * inv;
        wref[gid * 3 + 1] = y * inv;
        wref[gid * 3 + 2] = z * inv;
    }
}

// ---------------------------------------------------------------------------
// Kernel 5: per-batch weighted centroids + covariance (one block per batch)
// ---------------------------------------------------------------------------
__device__ __forceinline__ float block_reduce_sum(float x, float* lds4, int wv, int lane)
{
    #pragma unroll
    for (int off = 32; off > 0; off >>= 1) x += __shfl_down(x, off);
    __syncthreads();
    if (lane == 0) lds4[wv] = x;
    __syncthreads();
    return (lds4[0] + lds4[1]) + (lds4[2] + lds4[3]);
}

__global__ __launch_bounds__(256)
void kabsch_stats_kernel(const float* __restrict__ rowb, const float* __restrict__ wref,
                         const float* __restrict__ src, float* __restrict__ cov,
                         float* __restrict__ ca, float* __restrict__ cb)
{
    __shared__ float lds4[4];
    const int b = blockIdx.x, tid = threadIdx.x;
    const int wv = tid >> 6, lane = tid & 63;
    float r[4], w[4], ax[4], ay[4], az[4], bx[4], by[4], bz[4];
    float rsum = 0.f;
    #pragma unroll
    for (int i = 0; i < 4; ++i) {
        const int m = tid + 256 * i;
        r[i] = rowb[(b << 10) + m];
        rsum += r[i];
    }
    const float total = block_reduce_sum(rsum, lds4, wv, lane);
    const float inv = 1.0f / (total + 1e-6f);
    #pragma unroll
    for (int i = 0; i < 4; ++i) {
        const int m = tid + 256 * i;
        w[i]  = r[i] * inv;
        ax[i] = src[b * 3072 + m];
        ay[i] = src[b * 3072 + 1024 + m];
        az[i] = src[b * 3072 + 2048 + m];
        bx[i] = wref[((b << 10) + m) * 3 + 0];
        by[i] = wref[((b << 10) + m) * 3 + 1];
        bz[i] = wref[((b << 10) + m) * 3 + 2];
    }
    float cax = 0, cay = 0, caz = 0, cbx = 0, cby = 0, cbz = 0;
    #pragma unroll
    for (int i = 0; i < 4; ++i) {
        cax = fmaf(ax[i], w[i], cax); cay = fmaf(ay[i], w[i], cay); caz = fmaf(az[i], w[i], caz);
        cbx = fmaf(bx[i], w[i], cbx); cby = fmaf(by[i], w[i], cby); cbz = fmaf(bz[i], w[i], cbz);
    }
    cax = block_reduce_sum(cax, lds4, wv, lane);
    cay = block_reduce_sum(cay, lds4, wv, lane);
    caz = block_reduce_sum(caz, lds4, wv, lane);
    cbx = block_reduce_sum(cbx, lds4, wv, lane);
    cby = block_reduce_sum(cby, lds4, wv, lane);
    cbz = block_reduce_sum(cbz, lds4, wv, lane);
    float c[9] = {0,0,0,0,0,0,0,0,0};
    #pragma unroll
    for (int i = 0; i < 4; ++i) {
        const float dax = ax[i] - cax, day = ay[i] - cay, daz = az[i] - caz;
        const float dbx = (bx[i] - cbx) * w[i];
        const float dby = (by[i] - cby) * w[i];
        const float dbz = (bz[i] - cbz) * w[i];
        c[0] = fmaf(dax, dbx, c[0]); c[1] = fmaf(dax, dby, c[1]); c[2] = fmaf(dax, dbz, c[2]);
        c[3] = fmaf(day, dbx, c[3]); c[4] = fmaf(day, dby, c[4]); c[5] = fmaf(day, dbz, c[5]);
        c[6] = fmaf(daz, dbx, c[6]); c[7] = fmaf(daz, dby, c[7]); c[8] = fmaf(daz, dbz, c[8]);
    }
    #pragma unroll
    for (int k = 0; k < 9; ++k) c[k] = block_reduce_sum(c[k], lds4, wv, lane);
    if (tid == 0) {
        #pragma unroll
        for (int k = 0; k < 9; ++k) cov[b * 9 + k] = c[k];
        ca[b * 3 + 0] = cax; ca[b * 3 + 1] = cay; ca[b * 3 + 2] = caz;
        cb[b * 3 + 0] = cbx; cb[b * 3 + 1] = cby; cb[b * 3 + 2] = cbz;
    }
}

// ---------------------------------------------------------------------------
// Kernel 6: 3x3 SVD (double-precision Jacobi on A^T A) + Kabsch R,t
// ---------------------------------------------------------------------------
__device__ __forceinline__ void jrot_d(double S[3][3], double V[3][3], int p, int q)
{
    const double apq = S[p][q];
    if (fabs(apq) < 1e-300) return;
    const double theta = (S[q][q] - S[p][p]) / (2.0 * apq);
    const double tt = copysign(1.0, theta) / (fabs(theta) + sqrt(1.0 + theta * theta));
    const double c = 1.0 / sqrt(1.0 + tt * tt);
    const double s = tt * c;
    #pragma unroll
    for (int k = 0; k < 3; ++k) {
        const double skp = S[k][p], skq = S[k][q];
        S[k][p] = c * skp - s * skq;
        S[k][q] = s * skp + c * skq;
    }
    #pragma unroll
    for (int k = 0; k < 3; ++k) {
        const double spk = S[p][k], sqk = S[q][k];
        S[p][k] = c * spk - s * sqk;
        S[q][k] = s * spk + c * sqk;
    }
    #pragma unroll
    for (int k = 0; k < 3; ++k) {
        const double vkp = V[k][p], vkq = V[k][q];
        V[k][p] = c * vkp - s * vkq;
        V[k][q] = s * vkp + c * vkq;
    }
}

__global__ __launch_bounds__(64)
void svd_kernel(const float* __restrict__ cov, const float* __restrict__ ca,
                const float* __restrict__ cb, float* __restrict__ out)
{
    const int b = threadIdx.x;
    if (b >= 32) return;
    double A[3][3];
    #pragma unroll
    for (int i = 0; i < 3; ++i)
        #pragma unroll
        for (int j = 0; j < 3; ++j)
            A[i][j] = (double)cov[b * 9 + i * 3 + j];
    double S[3][3];
    #pragma unroll
    for (int i = 0; i < 3; ++i)
        #pragma unroll
        for (int j = 0; j < 3; ++j)
            S[i][j] = A[0][i] * A[0][j] + A[1][i] * A[1][j] + A[2][i] * A[2][j];
    double V[3][3] = {{1,0,0},{0,1,0},{0,0,1}};
    for (int sweep = 0; sweep < 8; ++sweep) {
        jrot_d(S, V, 0, 1);
        jrot_d(S, V, 0, 2);
        jrot_d(S, V, 1, 2);
    }
    int o0 = 0, o1 = 1, o2 = 2;
    double e0 = S[0][0], e1 = S[1][1], e2 = S[2][2];
    double tf; int ti;
    if (e0 < e1) { tf = e0; e0 = e1; e1 = tf; ti = o0; o0 = o1; o1 = ti; }
    if (e0 < e2) { tf = e0; e0 = e2; e2 = tf; ti = o0; o0 = o2; o2 = ti; }
    if (e1 < e2) { tf = e1; e1 = e2; e2 = tf; ti = o1; o1 = o2; o2 = ti; }
    double v1[3] = {V[0][o0], V[1][o0], V[2][o0]};
    double v2[3] = {V[0][o1], V[1][o1], V[2][o1]};
    double v3[3] = {V[0][o2], V[1][o2], V[2][o2]};
    double Av1[3], Av2[3];
    #pragma unroll
    for (int i = 0; i < 3; ++i) {
        Av1[i] = A[i][0] * v1[0] + A[i][1] * v1[1] + A[i][2] * v1[2];
        Av2[i] = A[i][0] * v2[0] + A[i][1] * v2[1] + A[i][2] * v2[2];
    }
    const double n1 = sqrt(Av1[0]*Av1[0] + Av1[1]*Av1[1] + Av1[2]*Av1[2]);
    const double in1 = 1.0 / fmax(n1, 1e-300);
    double u1[3] = {Av1[0]*in1, Av1[1]*in1, Av1[2]*in1};
    const double d12 = Av2[0]*u1[0] + Av2[1]*u1[1] + Av2[2]*u1[2];
    double u2[3] = {Av2[0] - d12*u1[0], Av2[1] - d12*u1[1], Av2[2] - d12*u1[2]};
    const double n2 = sqrt(u2[0]*u2[0] + u2[1]*u2[1] + u2[2]*u2[2]);
    const double in2 = 1.0 / fmax(n2, 1e-300);
    u2[0] *= in2; u2[1] *= in2; u2[2] *= in2;
    double u3[3] = {u1[1]*u2[2] - u1[2]*u2[1],
                    u1[2]*u2[0] - u1[0]*u2[2],
                    u1[0]*u2[1] - u1[1]*u2[0]};
    double R0[3][3];
    #pragma unroll
    for (int i = 0; i < 3; ++i)
        #pragma unroll
        for (int j = 0; j < 3; ++j)
            R0[i][j] = v1[i]*u1[j] + v2[i]*u2[j] + v3[i]*u3[j];
    const double det =
        R0[0][0]*(R0[1][1]*R0[2][2] - R0[1][2]*R0[2][1])
      - R0[0][1]*(R0[1][0]*R0[2][2] - R0[1][2]*R0[2][0])
      + R0[0][2]*(R0[1][0]*R0[2][1] - R0[1][1]*R0[2][0]);
    double Rm[3][3];
    if (det > 0.0) {
        #pragma unroll
        for (int i = 0; i < 3; ++i)
            #pragma unroll
            for (int j = 0; j < 3; ++j)
                Rm[i][j] = R0[i][j];
    } else {
        #pragma unroll
        for (int i = 0; i < 3; ++i)
            #pragma unroll
            for (int j = 0; j < 3; ++j)
                Rm[i][j] = R0[i][j] - 2.0 * v3[i] * u3[j];
    }
    const double cax = (double)ca[b*3+0], cay = (double)ca[b*3+1], caz = (double)ca[b*3+2];
    #pragma unroll
    for (int i = 0; i < 3; ++i)
        #pragma unroll
        for (int j = 0; j < 3; ++j)
            out[b * 9 + i * 3 + j] = (float)Rm[i][j];
    #pragma unroll
    for (int i = 0; i < 3; ++i)
        out[288 + b * 3 + i] = (float)((double)cb[b*3+i] - (Rm[i][0]*cax + Rm[i][1]*cay + Rm[i][2]*caz));
}

// ---------------------------------------------------------------------------
extern "C" void kernel_launch(void* const* d_in, const int* in_sizes, int n_in,
                              void* d_out, int out_size, void* d_ws, size_t ws_size,
                              hipStream_t stream)
{
    const float* srcE = (const float*)d_in[0];   // (B,D,M)
    const float* tgtE = (const float*)d_in[1];   // (B,D,N)
    const float* src  = (const float*)d_in[2];   // (B,3,M)
    const float* tgt  = (const float*)d_in[3];   // (B,3,N)
    const float* lp   = (const float*)d_in[4];   // scalar l
    const float* rp   = (const float*)d_in[5];   // scalar rho
    float* out  = (float*)d_out;                 // R(288) | t(96) | P(32M)
    float* Pout = out + 384;                     // K lives here, overwritten by P

    float* ws     = (float*)d_ws;
    float* w1     = ws;            // 32768
    float* w2     = ws + 32768;    // 32768
    float* u      = ws + 65536;    // 32768
    float* v      = ws + 98304;    // 32768
    float* rowb   = ws + 131072;   // 32768
    float* wref   = ws + 163840;   // 98304
    float* colsum = ws + 262144;   // 32768
    float* cov    = ws + 294912;   // 288
    float* ca     = ws + 295200;   // 96
    float* cb     = ws + 295296;   // 96

    norms_init_kernel<<<256, 256, 0, stream>>>(srcE, tgtE, w1, w2, v, colsum);
    gemm_kexp_kernel<<<dim3(8, 8, 32), 256, 0, stream>>>(srcE, tgtE, w1, w2, lp, Pout);
    for (int it = 0; it < 5; ++it) {
        uv_fused_kernel<<<dim3(32, 32), 256, 0, stream>>>(Pout, v, u, colsum, lp, rp);
        v_finalize_kernel<<<128, 256, 0, stream>>>(colsum, v, lp, rp);
    }
    p_pass_kernel<<<8192, 256, 0, stream>>>(Pout, u, v, tgt, rowb, wref);
    kabsch_stats_kernel<<<32, 256, 0, stream>>>(rowb, wref, src, cov, ca, cb);
    svd_kernel<<<1, 64, 0, stream>>>(cov, ca, cb, out);
}